// Round 16
// baseline (239.025 us; speedup 1.0000x reference)
//
#include <hip/hip_runtime.h>
#include <hip/hip_fp16.h>

#define NSET 38
#define NSNAP 9
#define PART (NSNAP*NSET*64)   // 21888 elements of partial per block
#define PPB 64
#define NCHUNK 1024            // 65536 / PPB
#define HSTR 72                // zth row stride (fp16): 144B rows, 16B-aligned
#define PSTR 72                // ztp row stride (fp16): 144B rows, 16B-aligned
#define WHALF (8*64*64)        // fp16 weight elements

typedef unsigned int uint;
typedef __fp16 h8 __attribute__((ext_vector_type(8)));
typedef float  f32x4 __attribute__((ext_vector_type(4)));

#define HNEGINF 0xFC00u
#define NEGPACK (HNEGINF | (HNEGINF << 16))

static __device__ __forceinline__ uint pk_add(uint a, uint b) {
  uint r; asm("v_pk_add_f16 %0, %1, %2" : "=v"(r) : "v"(a), "v"(b)); return r;
}
static __device__ __forceinline__ void pk_max_acc(uint& acc, uint t) {
  asm("v_pk_max_f16 %0, %1, %0" : "+v"(acc) : "v"(t));
}
static __device__ __forceinline__ float half_lo_f(uint u) {
  return (float)__builtin_bit_cast(__fp16, (unsigned short)(u & 0xFFFFu));
}
static __device__ __forceinline__ float half_hi_f(uint u) {
  return (float)__builtin_bit_cast(__fp16, (unsigned short)(u >> 16));
}

// kA: 256 threads, PPB=64 points/chunk, grid-stride over 1024 chunks,
// grid 768 -> exactly 3 blocks/CU (LDS 42.5 KB caps at 3 -> VGPR cap ~168,
// LDS-as-governor proven R3/R8/R10/R11/R13-R15).
// R15 lessons: (a) pool VALU stuck at ~2x model -> suspect h2 scalarization;
// fix: asm pk_add (fresh temp) + pk_max "%0,%1,%0" with "+v" in-place acc —
// structurally 2 VALU per pair-set, no movs, no scalarization.
// (b) pool LDS pipe ~35us/CU at pair-batching -> TRIPLE-buffer ztpA/B/C:
// one addend stream serves 3 snapshots (9 = 3 phases of 3), ~35 b128/
// wave-snap -> ~25us/CU.
__global__ __launch_bounds__(256)
void kA(const int* __restrict__ x, const float* __restrict__ w0,
        const float* __restrict__ cw, const float* __restrict__ cb,
        const float* __restrict__ pa, const __fp16* __restrict__ wf,
        __fp16* __restrict__ partialh)
{
  __shared__ __align__(16) __fp16 zth[PPB * HSTR];   // 9216 B [pt][dim] MFMA A
  __shared__ __align__(16) __fp16 ztpA[64 * PSTR];   // 9216 B [dim][pt]
  __shared__ __align__(16) __fp16 ztpB[64 * PSTR];   // 9216 B
  __shared__ __align__(16) __fp16 ztpC[64 * PSTR];   // 9216 B
  __shared__ __align__(16) __fp16 addp[40 * 64];     // 5120 B [set][2*pr]
  __shared__ uint memb2[PPB * 2];                    //  512 B [pt][half]

  const int tid = threadIdx.x;
  const int q  = tid & 63;             // point (conv0) / dim (pool)
  const int g  = __builtin_amdgcn_readfirstlane(tid >> 6);  // wave id, uniform
  const int lr = tid & 15;             // mfma: A-row offset / B,C col (dim)
  const int lg = (tid & 63) >> 4;      // mfma: k-group / C row-group
  const int sbase = g * 10;            // set groups 10/10/10/8
  const int nset = (g == 3) ? 8 : 10;

  auto prelu_frag = [&](int sv, f32x4* C, __fp16* ztpX) {
    // frag mapping: pt = 16g + 4*lg + r, dim = 16*dt + lr (wave-private rows)
    #pragma unroll
    for (int dt = 0; dt < 4; ++dt) {
      int dim = (dt << 4) + lr;
      float a = pa[(sv << 6) + dim];
      __fp16 zp[4];
      #pragma unroll
      for (int r = 0; r < 4; ++r) {
        float zv = C[dt][r];
        zp[r] = (__fp16)(zv > 0.f ? zv : a * zv);
        zth[((g << 4) + (lg << 2) + r) * HSTR + dim] = zp[r];
      }
      int pt0 = (g << 4) + (lg << 2);
      uint2 w2;
      w2.x = (uint)__builtin_bit_cast(unsigned short, zp[0]) |
             ((uint)__builtin_bit_cast(unsigned short, zp[1]) << 16);
      w2.y = (uint)__builtin_bit_cast(unsigned short, zp[2]) |
             ((uint)__builtin_bit_cast(unsigned short, zp[3]) << 16);
      *(uint2*)&ztpX[dim * PSTR + pt0] = w2;
    }
  };
  auto mfma_layer = [&](int sv, f32x4* C) {   // z(sv+1) pre-act from zth=z(sv)
    h8 a0 = *(const h8*)&zth[((g << 4) + lr) * HSTR + (lg << 3)];
    h8 a1 = *(const h8*)&zth[((g << 4) + lr) * HSTR + 32 + (lg << 3)];
    const __fp16* wb = wf + ((size_t)sv << 12);
    #pragma unroll
    for (int dt = 0; dt < 4; ++dt) {
      float bias = cb[((sv + 1) << 6) + (dt << 4) + lr];
      f32x4 a4 = {bias, bias, bias, bias};
      h8 b0 = *(const h8*)&wb[(((dt << 4) + lr) << 6) + (lg << 3)];
      h8 b1 = *(const h8*)&wb[(((dt << 4) + lr) << 6) + 32 + (lg << 3)];
      a4 = __builtin_amdgcn_mfma_f32_16x16x32_f16(a0, b0, a4, 0, 0, 0);
      a4 = __builtin_amdgcn_mfma_f32_16x16x32_f16(a1, b1, a4, 0, 0, 0);
      C[dt] = a4;
    }
  };
  auto fold_store = [&](int sv, uint* runv, bool first) {
    __fp16* pb = partialh + (size_t)blockIdx.x * PART + sv * (NSET * 64) + q;
    #pragma unroll
    for (int j = 0; j < 10; ++j) {
      if (j < nset) {                  // uniform guard (wave 3: 8 sets)
        __fp16 lo = __builtin_bit_cast(__fp16, (unsigned short)(runv[j] & 0xFFFFu));
        __fp16 hi = __builtin_bit_cast(__fp16, (unsigned short)(runv[j] >> 16));
        __fp16 m = lo > hi ? lo : hi;
        int off = (sbase + j) * 64;
        if (first) pb[off] = m;
        else { __fp16 o = pb[off]; pb[off] = (m > o) ? m : o; }
      }
    }
  };
  auto pool3 = [&](int sa, bool first) {     // pools snaps sa, sa+1, sa+2
    uint runA[10], runB[10], runC[10];
    #pragma unroll
    for (int j = 0; j < 10; ++j) { runA[j] = NEGPACK; runB[j] = NEGPACK; runC[j] = NEGPACK; }
    #pragma unroll 2
    for (int c4 = 0; c4 < 8; ++c4) {
      uint4 va = *(const uint4*)&ztpA[q * PSTR + (c4 << 3)];
      uint4 vb = *(const uint4*)&ztpB[q * PSTR + (c4 << 3)];
      uint4 vc = *(const uint4*)&ztpC[q * PSTR + (c4 << 3)];
      #pragma unroll
      for (int j = 0; j < 10; ++j) {
        uint4 aj = *(const uint4*)&addp[((sbase + j) << 6) + (c4 << 3)];
        pk_max_acc(runA[j], pk_add(va.x, aj.x));
        pk_max_acc(runA[j], pk_add(va.y, aj.y));
        pk_max_acc(runA[j], pk_add(va.z, aj.z));
        pk_max_acc(runA[j], pk_add(va.w, aj.w));
        pk_max_acc(runB[j], pk_add(vb.x, aj.x));
        pk_max_acc(runB[j], pk_add(vb.y, aj.y));
        pk_max_acc(runB[j], pk_add(vb.z, aj.z));
        pk_max_acc(runB[j], pk_add(vb.w, aj.w));
        pk_max_acc(runC[j], pk_add(vc.x, aj.x));
        pk_max_acc(runC[j], pk_add(vc.y, aj.y));
        pk_max_acc(runC[j], pk_add(vc.z, aj.z));
        pk_max_acc(runC[j], pk_add(vc.w, aj.w));
      }
    }
    fold_store(sa, runA, first);
    fold_store(sa + 1, runB, first);
    fold_store(sa + 2, runC, first);
  };

  #pragma unroll 1
  for (int cid = blockIdx.x; cid < NCHUNK; cid += gridDim.x) {
    const bool first = (cid == (int)blockIdx.x);
    const int p = cid * PPB + q;

    if (!first) __syncthreads();       // prior chunk's pool reads done
    if (tid < 128) {                   // membership: waves 0,1 (coalesced)
      const int half = tid >> 6;
      uint m = 0;
      #pragma unroll
      for (int j = 0; j < 19; ++j)
        m |= (uint)(x[(half * 19 + j) * 65536 + p] == 1) << j;
      memb2[q * 2 + half] = m;
    }
    __syncthreads();

    {                                  // addp[j][2pr|2pr+1]: in-set ? 0 : -inf
      uint* addp32 = (uint*)addp;
      #pragma unroll
      for (int i = tid; i < 1280; i += 256) {
        int j = i >> 5, pr = i & 31;
        uint lo0 = memb2[(2 * pr) * 2],     hi0 = memb2[(2 * pr) * 2 + 1];
        uint lo1 = memb2[(2 * pr + 1) * 2], hi1 = memb2[(2 * pr + 1) * 2 + 1];
        uint b0 = (j < 19) ? ((lo0 >> j) & 1u) : (j < 38) ? ((hi0 >> (j - 19)) & 1u) : 0u;
        uint b1 = (j < 19) ? ((lo1 >> j) & 1u) : (j < 38) ? ((hi1 >> (j - 19)) & 1u) : 0u;
        addp32[i] = (b0 ? 0u : HNEGINF) | ((b1 ? 0u : HNEGINF) << 16);
      }
    }

    // conv0: pre-act dims [16g,16g+16) of point q; weights via s_load
    float acc0[16];
    {
      float px = -1.f + (2.f / 255.f) * (float)(p & 255);
      float py = -1.f + (2.f / 255.f) * (float)(p >> 8);
      #pragma unroll
      for (int d = 0; d < 16; ++d) {
        int dd = (g << 4) + d;
        acc0[d] = fmaf(px, w0[2 * dd], fmaf(py, w0[2 * dd + 1], cb[dd]));
      }
    }
    __syncthreads();                   // addp ready

    // ---- phase 0: s = 0,1,2 ----
    #pragma unroll
    for (int d = 0; d < 16; ++d) {     // prelu s0 (cross-wave zth/ztpA)
      int dd = (g << 4) + d;
      float zv = acc0[d];
      float a = pa[dd];
      __fp16 zp = (__fp16)(zv > 0.f ? zv : a * zv);
      zth[q * HSTR + dd] = zp;
      ztpA[dd * PSTR + q] = zp;
    }
    __syncthreads();                   // zth(0)/ztpA visible

    f32x4 CfA[4], CfB[4];
    mfma_layer(0, CfA);                // z1 pre-act
    prelu_frag(1, CfA, ztpB);          // zth=z1
    mfma_layer(1, CfB);                // z2
    prelu_frag(2, CfB, ztpC);          // zth=z2
    mfma_layer(2, CfA);                // z3 (held through pool)
    __syncthreads();                   // ztpA/B/C visible
    pool3(0, first);

    // ---- phase 1: s = 3,4,5 ----
    __syncthreads();                   // pool reads done
    prelu_frag(3, CfA, ztpA);          // zth=z3
    mfma_layer(3, CfB);                // z4
    prelu_frag(4, CfB, ztpB);
    mfma_layer(4, CfA);                // z5
    prelu_frag(5, CfA, ztpC);
    mfma_layer(5, CfB);                // z6 (held)
    __syncthreads();
    pool3(3, first);

    // ---- phase 2: s = 6,7,8 ----
    __syncthreads();
    prelu_frag(6, CfB, ztpA);          // zth=z6
    mfma_layer(6, CfA);                // z7
    prelu_frag(7, CfA, ztpB);
    mfma_layer(7, CfB);                // z8
    prelu_frag(8, CfB, ztpC);
    __syncthreads();
    pool3(6, first);
  }
}

// one-shot: cw f32 -> fp16 (RNE) into workspace
__global__ __launch_bounds__(256) void kW(const float* __restrict__ cw,
                                          __fp16* __restrict__ wf)
{
  int i = blockIdx.x * 256 + threadIdx.x;
  if (i < WHALF) wf[i] = (__fp16)cw[i];
}

// stage-1 reduce: y-slice reduces nblk/32 fp16 block-partials -> f32 buf32
__global__ __launch_bounds__(256) void kB1(const __fp16* __restrict__ ph,
    float* __restrict__ buf32, int per)
{
  int idx = blockIdx.x * 256 + threadIdx.x;
  if (idx >= PART) return;
  const __fp16* p0 = ph + (size_t)blockIdx.y * per * PART + idx;
  float mx = -3e38f;
  #pragma unroll 8
  for (int b = 0; b < per; ++b)
    mx = fmaxf(mx, (float)p0[(size_t)b * PART]);
  buf32[(size_t)blockIdx.y * PART + idx] = mx;
}

// stage-2: reduce 32 slices + zero-point chain (folded kZ, f32 exact) + feat
__global__ __launch_bounds__(256) void kB2(const float* __restrict__ buf32,
    const float* __restrict__ cw, const float* __restrict__ cb,
    const float* __restrict__ pa, float* __restrict__ feat)
{
  __shared__ float zl[64];
  __shared__ float zc[NSNAP][64];
  __shared__ float zp[NSNAP][64];
  int tid = threadIdx.x;
  int d = tid & 63;
  float z = cb[d];
  #pragma unroll 1
  for (int s = 0; s < NSNAP; ++s) {
    if (tid < 64) {
      zc[s][d] = z;
      float a = pa[(s << 6) + d];
      float v = z > 0.f ? z : a * z;
      zp[s][d] = v;
      zl[d] = v;
    }
    __syncthreads();
    if (s < 8) {
      if (tid < 64) {
        float a2 = cb[((s + 1) << 6) + d];
        for (int k = 0; k < 64; ++k)
          a2 = fmaf(zl[k], cw[(s << 12) + (d << 6) + k], a2);
        z = a2;
      }
    }
    __syncthreads();
  }

  int idx = blockIdx.x * 256 + tid;
  if (idx >= PART) return;
  int s = idx / (NSET * 64);
  int r = idx - s * (NSET * 64);
  int set = r >> 6;
  int dd = r & 63;
  float mx = -3e38f;
  #pragma unroll
  for (int y = 0; y < 32; ++y)
    mx = fmaxf(mx, buf32[(size_t)y * PART + idx]);
  int b = set / 19, cc = set - b * 19;
  float even_v, odd_v;
  if (mx < -5e37f) {                 // empty set -> zero-point snapshot
    even_v = zc[s][dd];
    odd_v  = zp[s][dd];
  } else {
    odd_v = mx;                      // prelu-domain max
    float a = pa[(s << 6) + dd];
    even_v = mx > 0.f ? mx : mx / a; // inverse prelu
  }
  size_t fb = ((size_t)b * 18 + 2 * s) * 1216 + cc * 64 + dd;
  feat[fb] = even_v;
  feat[fb + 1216] = odd_v;
}

// out[b][17-lr][srow] = scale*<feat[b][lr], fcw[lr][srow]> + fcb[lr][srow]
__global__ __launch_bounds__(256) void kC(const float* __restrict__ feat,
    const float* __restrict__ fcw, const float* __restrict__ fcb,
    float* __restrict__ out)
{
  __shared__ float f0[1216], f1[1216];
  int lr = blockIdx.y;
  int chunk = blockIdx.x;       // 0..31, 16 rows each
  int tid = threadIdx.x;
  for (int i = tid; i < 1216; i += 256) {
    f0[i] = feat[(size_t)(0 * 18 + lr) * 1216 + i];
    f1[i] = feat[(size_t)(1 * 18 + lr) * 1216 + i];
  }
  __syncthreads();
  int wv = tid >> 6, lane = tid & 63;
  float scale = 1.f / sqrtf(1216.f);
  int l = 17 - lr;
  #pragma unroll 1
  for (int rr = 0; rr < 4; ++rr) {
    int srow = (chunk << 4) + (wv << 2) + rr;
    const float* wrow = fcw + ((size_t)lr * 512 + srow) * 1216;
    float pp0 = 0.f, pp1 = 0.f;
    #pragma unroll
    for (int k = 0; k < 19; ++k) {
      float w = wrow[(k << 6) + lane];
      pp0 = fmaf(w, f0[(k << 6) + lane], pp0);
      pp1 = fmaf(w, f1[(k << 6) + lane], pp1);
    }
    #pragma unroll
    for (int off = 32; off; off >>= 1) {
      pp0 += __shfl_xor(pp0, off, 64);
      pp1 += __shfl_xor(pp1, off, 64);
    }
    if (lane == 0) {
      float b = fcb[lr * 512 + srow];
      out[((size_t)0 * 18 + l) * 512 + srow] = fmaf(scale, pp0, b);
      out[((size_t)1 * 18 + l) * 512 + srow] = fmaf(scale, pp1, b);
    }
  }
}

extern "C" void kernel_launch(void* const* d_in, const int* in_sizes, int n_in,
                              void* d_out, int out_size, void* d_ws, size_t ws_size,
                              hipStream_t stream) {
  const int*   x   = (const int*)d_in[0];
  const float* w0  = (const float*)d_in[1];
  const float* cw  = (const float*)d_in[2];
  const float* cb  = (const float*)d_in[3];
  const float* pa  = (const float*)d_in[4];
  const float* fcw = (const float*)d_in[5];
  const float* fcb = (const float*)d_in[6];
  float* out = (float*)d_out;
  char* base = (char*)d_ws;

  // ws: fp16 partial | f32 buf32[32*PART] | f32 feat | fp16 wf
  #define NEED(n) ((size_t)(n) * PART * 2 + (size_t)32 * PART * 4 \
                   + (size_t)2 * 18 * 1216 * 4 + (size_t)WHALF * 2)

  int nblk;
  if      (ws_size >= NEED(768)) nblk = 768;   // 3 blocks/CU exactly
  else if (ws_size >= NEED(512)) nblk = 512;
  else                           nblk = 256;

  __fp16* partialh = (__fp16*)base;
  float*  buf32 = (float*)(base + (size_t)nblk * PART * 2);
  float*  feat  = buf32 + (size_t)32 * PART;
  __fp16* wf    = (__fp16*)(feat + (size_t)2 * 18 * 1216);
  const int per = nblk >> 5;    // blocks per kB1 y-slice (32 slices)

  hipLaunchKernelGGL(kW, dim3(WHALF / 256), dim3(256), 0, stream, cw, wf);
  hipLaunchKernelGGL(kA, dim3(nblk), dim3(256), 0, stream,
                     x, w0, cw, cb, pa, wf, partialh);
  hipLaunchKernelGGL(kB1, dim3(86, 32), dim3(256), 0, stream,
                     partialh, buf32, per);
  hipLaunchKernelGGL(kB2, dim3(86), dim3(256), 0, stream,
                     buf32, cw, cb, pa, feat);
  hipLaunchKernelGGL(kC, dim3(32, 18), dim3(256), 0, stream, feat, fcw, fcb, out);
}